// Round 1
// baseline (356.607 us; speedup 1.0000x reference)
//
#include <hip/hip_runtime.h>

#define U_DIM 400
#define V_DIM 400
#define TEXELS (U_DIM * V_DIM)

// Repack [M, U*V, 3,3] matrix + [M, U*V, 1,3] bias into 16-float (64B) aligned
// texel records in d_ws: [M, U*V, 16] where [0:9)=matrix, [9:12)=bias, [12:16)=0.
// One thread per output dword -> coalesced writes.
__global__ __launch_bounds__(256) void repack_kernel(
    const float* __restrict__ mp, const float* __restrict__ bp,
    float* __restrict__ packed, int total_dwords) {
  int idx = blockIdx.x * blockDim.x + threadIdx.x;
  if (idx >= total_dwords) return;
  int t = idx >> 4;   // texel (incl. material)
  int k = idx & 15;   // dword within record
  float val = 0.0f;
  if (k < 9)       val = mp[t * 9 + k];
  else if (k < 12) val = bp[t * 3 + (k - 9)];
  packed[idx] = val;
}

// Main kernel: one thread per point. 4 corner texels, 3x float4 aligned loads
// each, weighted accumulate of the 12-float record, then out = x*W + b.
__global__ __launch_bounds__(256) void interp_packed_kernel(
    const float* __restrict__ x, const int* __restrict__ mat,
    const float* __restrict__ u, const float* __restrict__ v,
    const float4* __restrict__ packed, float* __restrict__ out, int N) {
  int n = blockIdx.x * blockDim.x + threadIdx.x;
  if (n >= N) return;

  float iu = u[n] * (float)U_DIM; if (iu >= (float)U_DIM) iu = (float)(U_DIM - 1);
  float jv = v[n] * (float)V_DIM; if (jv >= (float)V_DIM) jv = (float)(V_DIM - 1);
  float i1f = floorf(iu), j1f = floorf(jv);
  int i1 = (int)i1f, j1 = (int)j1f;
  int i2 = i1 + 1; if (i2 == U_DIM) i2 = 0;
  int j2 = j1 + 1; if (j2 == V_DIM) j2 = 0;
  float ir = iu - i1f, jr = jv - j1f;

  float w[4];
  w[0] = (1.0f - ir) * (1.0f - jr);  // (i1,j1)
  w[1] = ir * (1.0f - jr);           // (i2,j1)
  w[2] = (1.0f - ir) * jr;           // (i1,j2)
  w[3] = ir * jr;                    // (i2,j2)
  int t[4];
  t[0] = i1 * V_DIM + j1;
  t[1] = i2 * V_DIM + j1;
  t[2] = i1 * V_DIM + j2;
  t[3] = i2 * V_DIM + j2;

  const float4* base = packed + (size_t)mat[n] * ((size_t)TEXELS * 4);

  float acc[12];
#pragma unroll
  for (int c = 0; c < 12; ++c) acc[c] = 0.0f;

#pragma unroll
  for (int c = 0; c < 4; ++c) {
    const float4* p = base + (size_t)t[c] * 4;
    float4 q0 = p[0];
    float4 q1 = p[1];
    float4 q2 = p[2];
    float wc = w[c];
    acc[0]  = fmaf(wc, q0.x, acc[0]);
    acc[1]  = fmaf(wc, q0.y, acc[1]);
    acc[2]  = fmaf(wc, q0.z, acc[2]);
    acc[3]  = fmaf(wc, q0.w, acc[3]);
    acc[4]  = fmaf(wc, q1.x, acc[4]);
    acc[5]  = fmaf(wc, q1.y, acc[5]);
    acc[6]  = fmaf(wc, q1.z, acc[6]);
    acc[7]  = fmaf(wc, q1.w, acc[7]);
    acc[8]  = fmaf(wc, q2.x, acc[8]);
    acc[9]  = fmaf(wc, q2.y, acc[9]);
    acc[10] = fmaf(wc, q2.z, acc[10]);
    acc[11] = fmaf(wc, q2.w, acc[11]);
  }

  float x0 = x[3 * n + 0];
  float x1 = x[3 * n + 1];
  float x2 = x[3 * n + 2];
  // out[j] = sum_i x[i] * W[i*3+j] + b[j];  W[k]=acc[k] k<9, b[j]=acc[9+j]
  float o0 = fmaf(x0, acc[0], fmaf(x1, acc[3], fmaf(x2, acc[6], acc[9])));
  float o1 = fmaf(x0, acc[1], fmaf(x1, acc[4], fmaf(x2, acc[7], acc[10])));
  float o2 = fmaf(x0, acc[2], fmaf(x1, acc[5], fmaf(x2, acc[8], acc[11])));
  out[3 * n + 0] = o0;
  out[3 * n + 1] = o1;
  out[3 * n + 2] = o2;
}

// Fallback if ws is too small for the packed table: direct scalar gathers
// from the original layouts (correct but slower).
__global__ __launch_bounds__(256) void interp_direct_kernel(
    const float* __restrict__ x, const int* __restrict__ mat,
    const float* __restrict__ u, const float* __restrict__ v,
    const float* __restrict__ mp, const float* __restrict__ bp,
    float* __restrict__ out, int N) {
  int n = blockIdx.x * blockDim.x + threadIdx.x;
  if (n >= N) return;

  float iu = u[n] * (float)U_DIM; if (iu >= (float)U_DIM) iu = (float)(U_DIM - 1);
  float jv = v[n] * (float)V_DIM; if (jv >= (float)V_DIM) jv = (float)(V_DIM - 1);
  float i1f = floorf(iu), j1f = floorf(jv);
  int i1 = (int)i1f, j1 = (int)j1f;
  int i2 = i1 + 1; if (i2 == U_DIM) i2 = 0;
  int j2 = j1 + 1; if (j2 == V_DIM) j2 = 0;
  float ir = iu - i1f, jr = jv - j1f;

  float w[4];
  w[0] = (1.0f - ir) * (1.0f - jr);
  w[1] = ir * (1.0f - jr);
  w[2] = (1.0f - ir) * jr;
  w[3] = ir * jr;
  int t[4];
  t[0] = i1 * V_DIM + j1;
  t[1] = i2 * V_DIM + j1;
  t[2] = i1 * V_DIM + j2;
  t[3] = i2 * V_DIM + j2;

  size_t mb = (size_t)mat[n] * TEXELS;
  float acc[12];
#pragma unroll
  for (int c = 0; c < 12; ++c) acc[c] = 0.0f;
#pragma unroll
  for (int c = 0; c < 4; ++c) {
    const float* pm = mp + (mb + t[c]) * 9;
    const float* pb = bp + (mb + t[c]) * 3;
    float wc = w[c];
#pragma unroll
    for (int k = 0; k < 9; ++k) acc[k] = fmaf(wc, pm[k], acc[k]);
#pragma unroll
    for (int k = 0; k < 3; ++k) acc[9 + k] = fmaf(wc, pb[k], acc[9 + k]);
  }

  float x0 = x[3 * n + 0];
  float x1 = x[3 * n + 1];
  float x2 = x[3 * n + 2];
  float o0 = fmaf(x0, acc[0], fmaf(x1, acc[3], fmaf(x2, acc[6], acc[9])));
  float o1 = fmaf(x0, acc[1], fmaf(x1, acc[4], fmaf(x2, acc[7], acc[10])));
  float o2 = fmaf(x0, acc[2], fmaf(x1, acc[5], fmaf(x2, acc[8], acc[11])));
  out[3 * n + 0] = o0;
  out[3 * n + 1] = o1;
  out[3 * n + 2] = o2;
}

extern "C" void kernel_launch(void* const* d_in, const int* in_sizes, int n_in,
                              void* d_out, int out_size, void* d_ws, size_t ws_size,
                              hipStream_t stream) {
  const float* x  = (const float*)d_in[0];
  const int*   m  = (const int*)d_in[1];
  const float* u  = (const float*)d_in[2];
  const float* v  = (const float*)d_in[3];
  const float* mp = (const float*)d_in[4];
  const float* bp = (const float*)d_in[5];
  float* out = (float*)d_out;

  int N = in_sizes[1];                       // number of points
  int M = in_sizes[4] / (TEXELS * 9);        // number of materials

  size_t need = (size_t)M * TEXELS * 16 * sizeof(float);
  if (ws_size >= need) {
    int total_dwords = M * TEXELS * 16;
    repack_kernel<<<(total_dwords + 255) / 256, 256, 0, stream>>>(
        mp, bp, (float*)d_ws, total_dwords);
    interp_packed_kernel<<<(N + 255) / 256, 256, 0, stream>>>(
        x, m, u, v, (const float4*)d_ws, out, N);
  } else {
    interp_direct_kernel<<<(N + 255) / 256, 256, 0, stream>>>(
        x, m, u, v, mp, bp, out, N);
  }
}